// Round 8
// baseline (137.161 us; speedup 1.0000x reference)
//
#include <hip/hip_runtime.h>

#define L_TOT 10752
#define NF    256
#define BATCHN 4096

typedef __attribute__((ext_vector_type(8))) short short8;   // 8 bf16
typedef __attribute__((ext_vector_type(4))) float f32x4;

__device__ __forceinline__ unsigned short f2bf(float f) {
  unsigned int u = __float_as_uint(f);
  unsigned int r = (u + 0x7FFFu + ((u >> 16) & 1u)) >> 16;  // RNE
  return (unsigned short)r;
}

__device__ __forceinline__ float tanh_fast(float x) {
  float e2 = __builtin_amdgcn_exp2f(x * 2.8853900817779268f); // 2*log2(e)
  float r  = __builtin_amdgcn_rcpf(e2 + 1.0f);
  return fmaf(-2.0f, r, 1.0f);
}

// ---------------- schedules (reduction masks; layout verified in R2) ----------
// Row layout per formula (n3 = NC/3): d6 rows [0,8n3) (8 rows/conj: 6 real+2 pad,
// quad-pair q<->q^1), d4 rows [8n3,12n3), d2 rows [12n3,14n3), tail pad to NT*16.
template<int G> struct Sch;
template<> struct Sch<0> {  // NC=6, n3=2
  static constexpr int NT = 2, NC = 6;
  static constexpr int p6[2]  = {0b11, 0};
  static constexpr int m4[2]  = {0, 0b0011};
  static constexpr int m2a[2] = {0, 0b0100};
  static constexpr int m2b[2] = {0, 0b0100};
};
template<> struct Sch<1> {  // NC=9, n3=3
  static constexpr int NT = 3, NC = 9;
  static constexpr int p6[3]  = {0b11, 0b01, 0};
  static constexpr int m4[3]  = {0, 0b1100, 0b0001};
  static constexpr int m2a[3] = {0, 0, 0b0110};
  static constexpr int m2b[3] = {0, 0, 0b0010};
};
template<> struct Sch<2> {  // NC=12, n3=4
  static constexpr int NT = 4, NC = 12;
  static constexpr int p6[4]  = {0b11, 0b11, 0, 0};
  static constexpr int m4[4]  = {0, 0, 0b1111, 0};
  static constexpr int m2a[4] = {0, 0, 0, 0b0011};
  static constexpr int m2b[4] = {0, 0, 0, 0b0011};
};
template<> struct Sch<3> {  // NC=15, n3=5
  static constexpr int NT = 5, NC = 15;
  static constexpr int p6[5]  = {0b11, 0b11, 0b01, 0, 0};
  static constexpr int m4[5]  = {0, 0, 0b1100, 0b0111, 0};
  static constexpr int m2a[5] = {0, 0, 0, 0b1000, 0b0011};
  static constexpr int m2b[5] = {0, 0, 0, 0b1000, 0b0001};
};

// -------- prep_w body (512 threads, HALF of k-range per block) ---------------
template<int G>
__device__ __forceinline__ void prep_w_body(
    const float* __restrict__ weight, const float* __restrict__ bias,
    const float* __restrict__ lm, int f, int ls, int fbase, int k0,
    unsigned short* __restrict__ WT, float* __restrict__ bias_p,
    unsigned short* s_t)
{
  using S = Sch<G>;
  constexpr int n3 = S::NC / 3;
  constexpr int LF = 12 * n3;
  constexpr int NROWS = S::NT * 16;
  const int tid = threadIdx.x;
  for (int e = tid; e < 64 * LF; e += 512) {
    int kk = e / LF;                // const divisor -> magic mul
    int j = e - kk * LF;
    int k = k0 + kk;
    float m = (fabsf(lm[k * NF + f]) > 1.0f) ? 1.0f : 0.0f;
    s_t[j * 72 + kk] = f2bf(weight[(size_t)k * L_TOT + ls + j] * m);
  }
  __syncthreads();
  const int kk = tid & 63, rb = tid >> 6;   // 8 row-streams, wave-uniform R
  for (int R = rb; R < NROWS; R += 8) {
    int j = -1;
    if (R < 8 * n3)        { int dd = R & 7; if (dd < 6) j = 6 * n3 + 6 * (R >> 3) + dd; }
    else if (R < 12 * n3)  j = R - 6 * n3;
    else if (R < 14 * n3)  j = R - 12 * n3;
    unsigned short v = (j >= 0) ? s_t[j * 72 + kk] : (unsigned short)0;
    WT[(size_t)(fbase + R) * 128 + k0 + kk] = v;
    if (kk == 0 && k0 == 0) bias_p[fbase + R] = (j >= 0) ? bias[ls + j] : 0.0f;
  }
}

// -- fused prep (512 thr): prep_x [0,256) + prep_b [256,288) + prep_w [288,800)
__global__ __launch_bounds__(512) void prep_all(
    const float4* __restrict__ x4, ushort4* __restrict__ a2,
    const float* __restrict__ mu, const float* __restrict__ sigma,
    unsigned short* __restrict__ B2, float* __restrict__ cf,
    const float* __restrict__ weight, const float* __restrict__ bias,
    const float* __restrict__ lm,
    unsigned short* __restrict__ WT, float* __restrict__ bias_p)
{
  __shared__ unsigned short s_t[60 * 72];   // 8.6 KB (j-major, half-k)
  int bi = blockIdx.x, tid = threadIdx.x;
  if (bi < 256) {                       // ---- prep_x
    int i = bi * 512 + tid;             // 4096*32
    float4 v = x4[i];
    int b = i >> 5, kc = i & 31;
    ushort4 sq, xx;
    sq.x = f2bf(v.x * v.x); sq.y = f2bf(v.y * v.y);
    sq.z = f2bf(v.z * v.z); sq.w = f2bf(v.w * v.w);
    xx.x = f2bf(v.x); xx.y = f2bf(v.y); xx.z = f2bf(v.z); xx.w = f2bf(v.w);
    a2[b * 64 + kc] = sq;
    a2[b * 64 + 32 + kc] = xx;
  } else if (bi < 288) {                // ---- prep_b (8 formulas/block, 1/wave)
    int f = (bi - 256) * 8 + (tid >> 6);
    int k = tid & 63;
    float acc = 0.0f;
    for (int kk = k; kk < 128; kk += 64) {
      float s = sigma[f * 128 + kk], m = mu[f * 128 + kk];
      float s2 = s * s;
      B2[f * 256 + kk] = f2bf(s2);
      B2[f * 256 + 128 + kk] = f2bf(-2.0f * m * s2);
      acc = fmaf(m * m, s2, acc);
    }
    for (int o = 1; o < 64; o <<= 1) acc += __shfl_xor(acc, o);
    if (k == 0) cf[f] = acc;
  } else {                              // ---- prep_w (2 blocks per formula)
    int idx = bi - 288;
    int f = idx >> 1, k0 = (idx & 1) * 64;
    int g = f >> 6, fo = f & 63;
    if (g == 0)      prep_w_body<0>(weight, bias, lm, f, 0    + fo * 24, fo * 32,        k0, WT, bias_p, s_t);
    else if (g == 1) prep_w_body<1>(weight, bias, lm, f, 1536 + fo * 36, 2048 + fo * 48, k0, WT, bias_p, s_t);
    else if (g == 2) prep_w_body<2>(weight, bias, lm, f, 3840 + fo * 48, 5120 + fo * 64, k0, WT, bias_p, s_t);
    else             prep_w_body<3>(weight, bias, lm, f, 6912 + fo * 60, 9216 + fo * 80, k0, WT, bias_p, s_t);
  }
}

// ---------------- main: minimal-VGPR per-t loop, TLP-hiding (target <=64 regs)
__device__ __forceinline__ short8 ldsw(const unsigned short* s_w, int row, int colb) {
  // XOR swizzle: row stride 256B would put all 16 n-lanes in one bank cluster
  int off = (row << 8) + (colb ^ ((row & 7) << 4));
  return *reinterpret_cast<const short8*>(reinterpret_cast<const char*>(s_w) + off);
}

template<int G>
__device__ __forceinline__ void dnnf_body(
    const unsigned short* __restrict__ A2,   // [4096][256] bf16 (x at +128)
    const unsigned short* __restrict__ WT,   // padded [rows][128] bf16 (linear)
    const float* __restrict__ bias_p,
    float* __restrict__ dnnf,                // [256][4096]
    int f, int fbase, int batch0,
    unsigned short* s_w, float* s_bias)
{
  using S = Sch<G>;
  constexpr int NT = S::NT;
  const int tid = threadIdx.x;
  const int lane = tid & 63;
  const int wv = tid >> 6;
  const int n = lane & 15;
  const int q = lane >> 4;

  // ---- stage WT tile (NT*16 rows x 256B) into LDS with XOR swizzle ----
  const char* wsrc = reinterpret_cast<const char*>(WT + (size_t)fbase * 128);
#pragma unroll
  for (int p = 0; p < NT; ++p) {
    int c = p * 256 + tid;              // 16B chunk id
    int row = c >> 4;
    int lin = c << 4;
    int swz = lin ^ ((row & 7) << 4);
    uint4 v = *reinterpret_cast<const uint4*>(wsrc + lin);
    *reinterpret_cast<uint4*>(reinterpret_cast<char*>(s_w) + swz) = v;
  }
  if (tid < NT * 16) s_bias[tid] = bias_p[fbase + tid];
  __syncthreads();

  const unsigned short* xr = A2 + (size_t)(batch0 + wv * 16 + n) * 256 + 128;
  float* dst = dnnf + (size_t)f * BATCHN + batch0 + wv * 16 + n;
  const float* bp = s_bias + q * 4;

#pragma unroll 1                          // runtime loop: minimal live ranges
  for (int it = 0; it < 8; ++it) {
    short8 xc[4];
#pragma unroll
    for (int kk = 0; kk < 4; ++kk)
      xc[kk] = *reinterpret_cast<const short8*>(xr + kk * 32 + q * 8);

    float fs = 0.0f;
#pragma unroll
    for (int t = 0; t < NT; ++t) {
      f32x4 acc = (f32x4){0.f, 0.f, 0.f, 0.f};
      __builtin_amdgcn_s_setprio(1);      // T5: favor MFMA cluster
#pragma unroll
      for (int kk = 0; kk < 4; ++kk)
        acc = __builtin_amdgcn_mfma_f32_16x16x32_bf16(
            ldsw(s_w, t * 16 + n, kk * 64 + q * 16), xc[kk], acc, 0, 0, 0);
      __builtin_amdgcn_s_setprio(0);
      float v0 = tanh_fast(acc[0] + bp[t * 16 + 0]);
      float v1 = tanh_fast(acc[1] + bp[t * 16 + 1]);
      float v2 = tanh_fast(acc[2] + bp[t * 16 + 2]);
      float v3 = tanh_fast(acc[3] + bp[t * 16 + 3]);
      float s = v0 + v1 + v2 + v3;
      if (S::p6[t]) {                     // depth-6: quad-pair q <-> q^1
        float po = __shfl_xor(s, 16);
        float t6 = tanh_fast(s + po - 4.5f);
        bool add = ((q & 1) == 0) && ((S::p6[t] >> (q >> 1)) & 1);
        fs += add ? t6 : 0.0f;
      }
      if (S::m4[t]) {                     // depth-4: whole quad
        float t4 = tanh_fast(s - 2.5f);
        fs += ((S::m4[t] >> q) & 1) ? t4 : 0.0f;
      }
      if (S::m2a[t]) {                    // depth-2: rows 0,1
        float ta = tanh_fast(v0 + v1 - 0.5f);
        fs += ((S::m2a[t] >> q) & 1) ? ta : 0.0f;
      }
      if (S::m2b[t]) {                    // depth-2: rows 2,3
        float tb = tanh_fast(v2 + v3 - 0.5f);
        fs += ((S::m2b[t] >> q) & 1) ? tb : 0.0f;
      }
    }
    fs += __shfl_xor(fs, 16);
    fs += __shfl_xor(fs, 32);
    float dv = tanh_fast(fs + (float)S::NC - 1.5f);
    if (lane < 16) *dst = dv;             // coalesced 64B
    xr += 64 * 256;
    dst += 64;
  }
}

__global__ __launch_bounds__(256, 4) void dnnf_main(
    const unsigned short* __restrict__ A2,
    const unsigned short* __restrict__ WT,
    const float* __restrict__ bias_p,
    float* __restrict__ dnnf)
{
  __shared__ __align__(16) unsigned short s_w[80 * 128];   // 20 KB max tile
  __shared__ __align__(16) float s_bias[80];
  int bi = blockIdx.x;
  int u = bi >> 3;                        // formula slot 0..255
  int batch0 = (bi & 7) * 512;
  int g = u & 3, fo = u >> 2;             // interleave G0..G3 for tail balance
  int f = (g << 6) | fo;
  if (g == 0)      dnnf_body<0>(A2, WT, bias_p, dnnf, f, fo * 32,        batch0, s_w, s_bias);
  else if (g == 1) dnnf_body<1>(A2, WT, bias_p, dnnf, f, 2048 + fo * 48, batch0, s_w, s_bias);
  else if (g == 2) dnnf_body<2>(A2, WT, bias_p, dnnf, f, 5120 + fo * 64, batch0, s_w, s_bias);
  else             dnnf_body<3>(A2, WT, bias_p, dnnf, f, 9216 + fo * 80, batch0, s_w, s_bias);
}

// ------- loc GEMM + softmax + multiply (16 waves; dnnf tile staged in LDS) ----
__global__ __launch_bounds__(1024) void loc_fused(
    const unsigned short* __restrict__ A2,   // [4096][256] bf16
    const unsigned short* __restrict__ B2,   // [256][256] bf16
    const float* __restrict__ cf,            // [256]
    const float* __restrict__ temp,
    const float* __restrict__ dnnf,          // [256][4096]
    float* __restrict__ out)                 // [4096][256]
{
  __shared__ float s_part[16][16];
  __shared__ float s_d[256 * 17];           // dnnf tile [f][b], pad 17 vs banks
  int tid = threadIdx.x, lane = tid & 63, w = tid >> 6, n = lane & 15, q = lane >> 4;
  int b0 = blockIdx.x * 16;

  // stage dnnf[f][b0..b0+16) coalesced: 4 threads/row x 16B
  {
    int fr = tid >> 2, c4 = (tid & 3) * 4;
    f32x4 v = *reinterpret_cast<const f32x4*>(dnnf + (size_t)fr * BATCHN + b0 + c4);
    s_d[fr * 17 + c4 + 0] = v[0];
    s_d[fr * 17 + c4 + 1] = v[1];
    s_d[fr * 17 + c4 + 2] = v[2];
    s_d[fr * 17 + c4 + 3] = v[3];
  }

  const unsigned short* arow = A2 + (size_t)(b0 + n) * 256;
  const unsigned short* brow = B2 + (size_t)(w * 16 + n) * 256;
  f32x4 acc = (f32x4){0.f, 0.f, 0.f, 0.f};
#pragma unroll
  for (int kk = 0; kk < 8; ++kk) {
    short8 af = *reinterpret_cast<const short8*>(arow + kk * 32 + q * 8);
    short8 bf = *reinterpret_cast<const short8*>(brow + kk * 32 + q * 8);
    acc = __builtin_amdgcn_mfma_f32_16x16x32_bf16(af, bf, acc, 0, 0, 0);
  }

  float T = temp[0];
  float sg = 1.0f / (1.0f + __builtin_amdgcn_exp2f(-T * 1.4426950408889634f));
  float ez[4];
  float sr[4];
  float c = cf[w * 16 + n];
#pragma unroll
  for (int r = 0; r < 4; ++r) {
    float n2 = fmaxf(acc[r] + c, 0.0f);
    float loc = __builtin_amdgcn_exp2f(-__builtin_amdgcn_sqrtf(n2) * 1.4426950408889634f);
    float e = __builtin_amdgcn_exp2f(sg * loc * 1.4426950408889634f);
    ez[r] = e;
    sr[r] = e;
  }
#pragma unroll
  for (int o = 1; o < 16; o <<= 1)
#pragma unroll
    for (int r = 0; r < 4; ++r) sr[r] += __shfl_xor(sr[r], o);
  if (n == 0) {
#pragma unroll
    for (int r = 0; r < 4; ++r) s_part[w][q * 4 + r] = sr[r];
  }
  __syncthreads();                        // covers s_part AND s_d
  float rtot[4];
#pragma unroll
  for (int r = 0; r < 4; ++r) {
    float tot = 0.0f;
#pragma unroll
    for (int ww = 0; ww < 16; ++ww) tot += s_part[ww][q * 4 + r];
    rtot[r] = 1.0f / tot;
  }
  int fc = w * 16 + n;
#pragma unroll
  for (int r = 0; r < 4; ++r) {
    int bg = b0 + q * 4 + r;
    out[(size_t)bg * 256 + fc] = s_d[fc * 17 + q * 4 + r] * ez[r] * rtot[r];
  }
}

extern "C" void kernel_launch(void* const* d_in, const int* in_sizes, int n_in,
                              void* d_out, int out_size, void* d_ws, size_t ws_size,
                              hipStream_t stream) {
  const float* x      = (const float*)d_in[0];
  const float* weight = (const float*)d_in[1];
  const float* bias   = (const float*)d_in[2];
  const float* lm     = (const float*)d_in[3];
  const float* mu     = (const float*)d_in[4];
  const float* sigma  = (const float*)d_in[5];
  const float* temp   = (const float*)d_in[6];
  float* out = (float*)d_out;

  char* ws = (char*)d_ws;
  unsigned short* A2     = (unsigned short*)(ws);                 // 2 MB
  float*          dnnf   = (float*)(ws + 2097152);                // 4 MB [f][b]
  unsigned short* B2     = (unsigned short*)(ws + 6291456);       // 128 KB
  float*          cf     = (float*)(ws + 6422528);                // 1 KB
  unsigned short* WT     = (unsigned short*)(ws + 6423552);       // 3.5 MB
  float*          bias_p = (float*)(ws + 10093568);               // 56 KB

  prep_all<<<800, 512, 0, stream>>>((const float4*)x, (ushort4*)A2,
                                    mu, sigma, B2, cf,
                                    weight, bias, lm, WT, bias_p);
  dnnf_main<<<2048, 256, 0, stream>>>(A2, WT, bias_p, dnnf);
  loc_fused<<<256, 1024, 0, stream>>>(A2, B2, cf, temp, dnnf, out);
}

// Round 9
// 130.519 us; speedup vs baseline: 1.0509x; 1.0509x over previous
//
#include <hip/hip_runtime.h>

#define L_TOT 10752
#define NF    256
#define BATCHN 4096

typedef __attribute__((ext_vector_type(8))) short short8;   // 8 bf16
typedef __attribute__((ext_vector_type(4))) float f32x4;

__device__ __forceinline__ unsigned short f2bf(float f) {
  unsigned int u = __float_as_uint(f);
  unsigned int r = (u + 0x7FFFu + ((u >> 16) & 1u)) >> 16;  // RNE
  return (unsigned short)r;
}

__device__ __forceinline__ float tanh_fast(float x) {
  float e2 = __builtin_amdgcn_exp2f(x * 2.8853900817779268f); // 2*log2(e)
  float r  = __builtin_amdgcn_rcpf(e2 + 1.0f);
  return fmaf(-2.0f, r, 1.0f);
}

// ---------------- schedules (reduction masks; layout verified in R2) ----------
template<int G> struct Sch;
template<> struct Sch<0> {  // NC=6, n3=2
  static constexpr int NT = 2, NC = 6;
  static constexpr int p6[2]  = {0b11, 0};
  static constexpr int m4[2]  = {0, 0b0011};
  static constexpr int m2a[2] = {0, 0b0100};
  static constexpr int m2b[2] = {0, 0b0100};
};
template<> struct Sch<1> {  // NC=9, n3=3
  static constexpr int NT = 3, NC = 9;
  static constexpr int p6[3]  = {0b11, 0b01, 0};
  static constexpr int m4[3]  = {0, 0b1100, 0b0001};
  static constexpr int m2a[3] = {0, 0, 0b0110};
  static constexpr int m2b[3] = {0, 0, 0b0010};
};
template<> struct Sch<2> {  // NC=12, n3=4
  static constexpr int NT = 4, NC = 12;
  static constexpr int p6[4]  = {0b11, 0b11, 0, 0};
  static constexpr int m4[4]  = {0, 0, 0b1111, 0};
  static constexpr int m2a[4] = {0, 0, 0, 0b0011};
  static constexpr int m2b[4] = {0, 0, 0, 0b0011};
};
template<> struct Sch<3> {  // NC=15, n3=5
  static constexpr int NT = 5, NC = 15;
  static constexpr int p6[5]  = {0b11, 0b11, 0b01, 0, 0};
  static constexpr int m4[5]  = {0, 0, 0b1100, 0b0111, 0};
  static constexpr int m2a[5] = {0, 0, 0, 0b1000, 0b0011};
  static constexpr int m2b[5] = {0, 0, 0, 0b1000, 0b0001};
};

// -------- prep_w body (512 threads, HALF of k-range per block) ---------------
template<int G>
__device__ __forceinline__ void prep_w_body(
    const float* __restrict__ weight, const float* __restrict__ bias,
    const float* __restrict__ lm, int f, int ls, int fbase, int k0,
    unsigned short* __restrict__ WT, float* __restrict__ bias_p,
    unsigned short* s_t)
{
  using S = Sch<G>;
  constexpr int n3 = S::NC / 3;
  constexpr int LF = 12 * n3;
  constexpr int NROWS = S::NT * 16;
  const int tid = threadIdx.x;
  for (int e = tid; e < 64 * LF; e += 512) {
    int kk = e / LF;                // const divisor -> magic mul
    int j = e - kk * LF;
    int k = k0 + kk;
    float m = (fabsf(lm[k * NF + f]) > 1.0f) ? 1.0f : 0.0f;
    s_t[j * 72 + kk] = f2bf(weight[(size_t)k * L_TOT + ls + j] * m);
  }
  __syncthreads();
  const int kk = tid & 63, rb = tid >> 6;   // 8 row-streams, wave-uniform R
  for (int R = rb; R < NROWS; R += 8) {
    int j = -1;
    if (R < 8 * n3)        { int dd = R & 7; if (dd < 6) j = 6 * n3 + 6 * (R >> 3) + dd; }
    else if (R < 12 * n3)  j = R - 6 * n3;
    else if (R < 14 * n3)  j = R - 12 * n3;
    unsigned short v = (j >= 0) ? s_t[j * 72 + kk] : (unsigned short)0;
    WT[(size_t)(fbase + R) * 128 + k0 + kk] = v;
    if (kk == 0 && k0 == 0) bias_p[fbase + R] = (j >= 0) ? bias[ls + j] : 0.0f;
  }
}

// -- fused prep (512 thr): prep_x [0,256) + prep_b [256,288) + prep_w [288,800)
__global__ __launch_bounds__(512) void prep_all(
    const float4* __restrict__ x4, ushort4* __restrict__ a2,
    const float* __restrict__ mu, const float* __restrict__ sigma,
    unsigned short* __restrict__ B2, float* __restrict__ cf,
    const float* __restrict__ weight, const float* __restrict__ bias,
    const float* __restrict__ lm,
    unsigned short* __restrict__ WT, float* __restrict__ bias_p)
{
  __shared__ unsigned short s_t[60 * 72];   // 8.6 KB (j-major, half-k)
  int bi = blockIdx.x, tid = threadIdx.x;
  if (bi < 256) {                       // ---- prep_x
    int i = bi * 512 + tid;             // 4096*32
    float4 v = x4[i];
    int b = i >> 5, kc = i & 31;
    ushort4 sq, xx;
    sq.x = f2bf(v.x * v.x); sq.y = f2bf(v.y * v.y);
    sq.z = f2bf(v.z * v.z); sq.w = f2bf(v.w * v.w);
    xx.x = f2bf(v.x); xx.y = f2bf(v.y); xx.z = f2bf(v.z); xx.w = f2bf(v.w);
    a2[b * 64 + kc] = sq;
    a2[b * 64 + 32 + kc] = xx;
  } else if (bi < 288) {                // ---- prep_b (8 formulas/block, 1/wave)
    int f = (bi - 256) * 8 + (tid >> 6);
    int k = tid & 63;
    float acc = 0.0f;
    for (int kk = k; kk < 128; kk += 64) {
      float s = sigma[f * 128 + kk], m = mu[f * 128 + kk];
      float s2 = s * s;
      B2[f * 256 + kk] = f2bf(s2);
      B2[f * 256 + 128 + kk] = f2bf(-2.0f * m * s2);
      acc = fmaf(m * m, s2, acc);
    }
    for (int o = 1; o < 64; o <<= 1) acc += __shfl_xor(acc, o);
    if (k == 0) cf[f] = acc;
  } else {                              // ---- prep_w (2 blocks per formula)
    int idx = bi - 288;
    int f = idx >> 1, k0 = (idx & 1) * 64;
    int g = f >> 6, fo = f & 63;
    if (g == 0)      prep_w_body<0>(weight, bias, lm, f, 0    + fo * 24, fo * 32,        k0, WT, bias_p, s_t);
    else if (g == 1) prep_w_body<1>(weight, bias, lm, f, 1536 + fo * 36, 2048 + fo * 48, k0, WT, bias_p, s_t);
    else if (g == 2) prep_w_body<2>(weight, bias, lm, f, 3840 + fo * 48, 5120 + fo * 64, k0, WT, bias_p, s_t);
    else             prep_w_body<3>(weight, bias, lm, f, 6912 + fo * 60, 9216 + fo * 80, k0, WT, bias_p, s_t);
  }
}

// ---------------- dnnf: per-t software pipeline (R6/R7 proven form) -----------
__device__ __forceinline__ short8 ldsw(const unsigned short* s_w, int row, int colb) {
  int off = (row << 8) + (colb ^ ((row & 7) << 4));
  return *reinterpret_cast<const short8*>(reinterpret_cast<const char*>(s_w) + off);
}

template<int G>
__device__ __forceinline__ void mfma_stage(const unsigned short* s_w, const float* s_bias,
                                           const short8* xc, f32x4& acc, int t, int n, int q)
{
  acc = *reinterpret_cast<const f32x4*>(&s_bias[t * 16 + q * 4]);  // C-in = bias
#pragma unroll
  for (int kk = 0; kk < 4; ++kk)
    acc = __builtin_amdgcn_mfma_f32_16x16x32_bf16(
        ldsw(s_w, t * 16 + n, kk * 64 + q * 16), xc[kk], acc, 0, 0, 0);
}

template<int G>
__device__ __forceinline__ void reduce_stage(const f32x4& ac, float& fs, int t, int q)
{
  using S = Sch<G>;
  float v0 = tanh_fast(ac[0]);
  float v1 = tanh_fast(ac[1]);
  float v2 = tanh_fast(ac[2]);
  float v3 = tanh_fast(ac[3]);
  float s = v0 + v1 + v2 + v3;
  if (S::p6[t]) {                       // depth-6: quad-pair q <-> q^1
    float po = __shfl_xor(s, 16);
    float t6 = tanh_fast(s + po - 4.5f);
    bool add = ((q & 1) == 0) && ((S::p6[t] >> (q >> 1)) & 1);
    fs += add ? t6 : 0.0f;
  }
  if (S::m4[t]) {                       // depth-4: whole quad
    float t4 = tanh_fast(s - 2.5f);
    fs += ((S::m4[t] >> q) & 1) ? t4 : 0.0f;
  }
  if (S::m2a[t]) {                      // depth-2: rows 0,1
    float ta = tanh_fast(v0 + v1 - 0.5f);
    fs += ((S::m2a[t] >> q) & 1) ? ta : 0.0f;
  }
  if (S::m2b[t]) {                      // depth-2: rows 2,3
    float tb = tanh_fast(v2 + v3 - 0.5f);
    fs += ((S::m2b[t] >> q) & 1) ? tb : 0.0f;
  }
}

template<int G>
__device__ __forceinline__ void dnnf_body(
    const unsigned short* __restrict__ A2,
    const unsigned short* __restrict__ WT,
    const float* __restrict__ bias_p,
    float* __restrict__ dnnf,
    int f, int fbase, int batch0,
    unsigned short* s_w, float* s_bias)
{
  using S = Sch<G>;
  constexpr int NT = S::NT;
  constexpr int NS = 8 * NT;
  const int tid = threadIdx.x;
  const int lane = tid & 63;
  const int wv = tid >> 6;
  const int n = lane & 15;
  const int q = lane >> 4;

  const char* wsrc = reinterpret_cast<const char*>(WT + (size_t)fbase * 128);
#pragma unroll
  for (int p = 0; p < NT; ++p) {
    int c = p * 256 + tid;              // 16B chunk id
    int row = c >> 4;
    int lin = c << 4;
    int swz = lin ^ ((row & 7) << 4);
    uint4 v = *reinterpret_cast<const uint4*>(wsrc + lin);
    *reinterpret_cast<uint4*>(reinterpret_cast<char*>(s_w) + swz) = v;
  }
  if (tid < NT * 16) s_bias[tid] = bias_p[fbase + tid];
  __syncthreads();

  const unsigned short* xr0 = A2 + (size_t)(batch0 + wv * 16 + n) * 256 + 128;
  short8 x0[4], x1[4];
  f32x4 a0, a1;
  float fs = 0.0f;

#pragma unroll
  for (int kk = 0; kk < 4; ++kk)
    x0[kk] = *reinterpret_cast<const short8*>(xr0 + kk * 32 + q * 8);
  mfma_stage<G>(s_w, s_bias, x0, a0, 0, n, q);

#pragma unroll
  for (int s = 0; s < NS; ++s) {
    const int it = s / NT, t = s - it * NT;
    if (t == NT - 2 && it < 7) {        // prefetch iter it+1 one stage early
      const unsigned short* xr = xr0 + (size_t)(it + 1) * 64 * 256;
      if (((it + 1) & 1) == 0) {
#pragma unroll
        for (int kk = 0; kk < 4; ++kk)
          x0[kk] = *reinterpret_cast<const short8*>(xr + kk * 32 + q * 8);
      } else {
#pragma unroll
        for (int kk = 0; kk < 4; ++kk)
          x1[kk] = *reinterpret_cast<const short8*>(xr + kk * 32 + q * 8);
      }
    }
    if (s + 1 < NS) {                   // matrix pipe: stage s+1 (other acc)
      const int it1 = (s + 1) / NT;
      const int t1 = (s + 1) - it1 * NT;
      if (((s + 1) & 1) == 0) {
        if ((it1 & 1) == 0) mfma_stage<G>(s_w, s_bias, x0, a0, t1, n, q);
        else                mfma_stage<G>(s_w, s_bias, x1, a0, t1, n, q);
      } else {
        if ((it1 & 1) == 0) mfma_stage<G>(s_w, s_bias, x0, a1, t1, n, q);
        else                mfma_stage<G>(s_w, s_bias, x1, a1, t1, n, q);
      }
    }
    if ((s & 1) == 0) reduce_stage<G>(a0, fs, t, q);
    else              reduce_stage<G>(a1, fs, t, q);
    if (t == NT - 1) {
      fs += __shfl_xor(fs, 16);
      fs += __shfl_xor(fs, 32);
      float dv = tanh_fast(fs + (float)S::NC - 1.5f);
      if (lane < 16)
        dnnf[(size_t)f * BATCHN + batch0 + it * 64 + wv * 16 + n] = dv;
      fs = 0.0f;
    }
  }
}

// -------- locsm: softmax-weight blocks (independent of dnnf), sm -> out -------
__device__ __forceinline__ void locsm_body(
    const unsigned short* __restrict__ A2,
    const unsigned short* __restrict__ B2,
    const float* __restrict__ cf,
    const float* __restrict__ temp,
    float* __restrict__ out,              // sm[b][f] = ez*rtot staged here
    int b0, float (*s_part)[16])
{
  int tid = threadIdx.x, lane = tid & 63, w = tid >> 6, n = lane & 15, q = lane >> 4;
  const unsigned short* arow = A2 + (size_t)(b0 + n) * 256;
  f32x4 acc[4];
#pragma unroll
  for (int t = 0; t < 4; ++t) acc[t] = (f32x4){0.f, 0.f, 0.f, 0.f};
#pragma unroll
  for (int kk = 0; kk < 8; ++kk) {
    short8 af = *reinterpret_cast<const short8*>(arow + kk * 32 + q * 8);
#pragma unroll
    for (int t = 0; t < 4; ++t) {
      const unsigned short* brow = B2 + (size_t)(w * 64 + t * 16 + n) * 256;
      short8 bf = *reinterpret_cast<const short8*>(brow + kk * 32 + q * 8);
      acc[t] = __builtin_amdgcn_mfma_f32_16x16x32_bf16(af, bf, acc[t], 0, 0, 0);
    }
  }
  float T = temp[0];
  float sg = 1.0f / (1.0f + __builtin_amdgcn_exp2f(-T * 1.4426950408889634f));
  float ez[4][4];
  float sr[4] = {0.f, 0.f, 0.f, 0.f};
#pragma unroll
  for (int t = 0; t < 4; ++t) {
    float c = cf[w * 64 + t * 16 + n];
#pragma unroll
    for (int r = 0; r < 4; ++r) {
      float n2 = fmaxf(acc[t][r] + c, 0.0f);
      float loc = __builtin_amdgcn_exp2f(-__builtin_amdgcn_sqrtf(n2) * 1.4426950408889634f);
      float e = __builtin_amdgcn_exp2f(sg * loc * 1.4426950408889634f);
      ez[t][r] = e;
      sr[r] += e;
    }
  }
#pragma unroll
  for (int o = 1; o < 16; o <<= 1)
#pragma unroll
    for (int r = 0; r < 4; ++r) sr[r] += __shfl_xor(sr[r], o);
  if (n == 0) {
#pragma unroll
    for (int r = 0; r < 4; ++r) s_part[w][q * 4 + r] = sr[r];
  }
  __syncthreads();
  float rtot[4];
#pragma unroll
  for (int r = 0; r < 4; ++r) {
    float tot = s_part[0][q * 4 + r] + s_part[1][q * 4 + r] +
                s_part[2][q * 4 + r] + s_part[3][q * 4 + r];
    rtot[r] = 1.0f / tot;
  }
#pragma unroll
  for (int t = 0; t < 4; ++t) {
    int fc = w * 64 + t * 16 + n;
#pragma unroll
    for (int r = 0; r < 4; ++r) {
      int bg = b0 + q * 4 + r;
      out[(size_t)bg * 256 + fc] = ez[t][r] * rtot[r];   // sm only; dnnf later
    }
  }
}

// -------- merged grid: [0,256) locsm + [256,2304) dnnf ------------------------
__global__ __launch_bounds__(256, 2) void main2(
    const unsigned short* __restrict__ A2,
    const unsigned short* __restrict__ WT,
    const float* __restrict__ bias_p,
    const unsigned short* __restrict__ B2,
    const float* __restrict__ cf,
    const float* __restrict__ temp,
    float* __restrict__ dnnf,
    float* __restrict__ out)
{
  __shared__ __align__(16) unsigned short s_w[80 * 128];   // 20 KB max tile
  __shared__ __align__(16) float s_bias[80];
  __shared__ float s_part[4][16];
  int bi = blockIdx.x;
  if (bi < 256) {                        // ---- softmax-weight blocks (early)
    locsm_body(A2, B2, cf, temp, out, bi * 16, s_part);
    return;
  }
  bi -= 256;
  int u = bi >> 3;                        // formula slot 0..255
  int batch0 = (bi & 7) * 512;
  int g = u & 3, fo = u >> 2;             // interleave G0..G3 for tail balance
  int f = (g << 6) | fo;
  if (g == 0)      dnnf_body<0>(A2, WT, bias_p, dnnf, f, fo * 32,        batch0, s_w, s_bias);
  else if (g == 1) dnnf_body<1>(A2, WT, bias_p, dnnf, f, 2048 + fo * 48, batch0, s_w, s_bias);
  else if (g == 2) dnnf_body<2>(A2, WT, bias_p, dnnf, f, 5120 + fo * 64, batch0, s_w, s_bias);
  else             dnnf_body<3>(A2, WT, bias_p, dnnf, f, 9216 + fo * 80, batch0, s_w, s_bias);
}

// -------- final: out[b][f] *= dnnf[f][b] (LDS-transposed, coalesced) ----------
__global__ __launch_bounds__(1024) void mult(
    const float* __restrict__ dnnf, float* __restrict__ out)
{
  __shared__ float s_d[256 * 17];
  int tid = threadIdx.x, b0 = blockIdx.x * 16;
  {
    int fr = tid >> 2, c4 = (tid & 3) * 4;
    f32x4 v = *reinterpret_cast<const f32x4*>(dnnf + (size_t)fr * BATCHN + b0 + c4);
    s_d[fr * 17 + c4 + 0] = v[0];
    s_d[fr * 17 + c4 + 1] = v[1];
    s_d[fr * 17 + c4 + 2] = v[2];
    s_d[fr * 17 + c4 + 3] = v[3];
  }
  __syncthreads();
  int f = tid & 255, bb = tid >> 8;       // bb 0..3
#pragma unroll
  for (int i = 0; i < 4; ++i) {
    int b = bb * 4 + i;                   // 0..15
    out[(size_t)(b0 + b) * 256 + f] *= s_d[f * 17 + b];
  }
}

extern "C" void kernel_launch(void* const* d_in, const int* in_sizes, int n_in,
                              void* d_out, int out_size, void* d_ws, size_t ws_size,
                              hipStream_t stream) {
  const float* x      = (const float*)d_in[0];
  const float* weight = (const float*)d_in[1];
  const float* bias   = (const float*)d_in[2];
  const float* lm     = (const float*)d_in[3];
  const float* mu     = (const float*)d_in[4];
  const float* sigma  = (const float*)d_in[5];
  const float* temp   = (const float*)d_in[6];
  float* out = (float*)d_out;

  char* ws = (char*)d_ws;
  unsigned short* A2     = (unsigned short*)(ws);                 // 2 MB
  float*          dnnf   = (float*)(ws + 2097152);                // 4 MB [f][b]
  unsigned short* B2     = (unsigned short*)(ws + 6291456);       // 128 KB
  float*          cf     = (float*)(ws + 6422528);                // 1 KB
  unsigned short* WT     = (unsigned short*)(ws + 6423552);       // 3.5 MB
  float*          bias_p = (float*)(ws + 10093568);               // 56 KB

  prep_all<<<800, 512, 0, stream>>>((const float4*)x, (ushort4*)A2,
                                    mu, sigma, B2, cf,
                                    weight, bias, lm, WT, bias_p);
  main2<<<2304, 256, 0, stream>>>(A2, WT, bias_p, B2, cf, temp, dnnf, out);
  mult<<<256, 1024, 0, stream>>>(dnnf, out);
}